// Round 8
// baseline (491.951 us; speedup 1.0000x reference)
//
#include <hip/hip_runtime.h>

#define NSEG 40000
#define NREG 1000
#define NEDGE 640000
#define HID 256
#define KCAT 1280   // 5 * HID
#define KP1 1024    // padded K for gemm1 (Pt zero-padded cols 1000..1023)
#define NBLK 157    // ceil(NSEG/256)

typedef float f32x4 __attribute__((ext_vector_type(4)));
typedef short s16x8 __attribute__((ext_vector_type(8)));
typedef unsigned short u16x4 __attribute__((ext_vector_type(4)));
typedef unsigned short u16x8 __attribute__((ext_vector_type(8)));

typedef __attribute__((address_space(3))) unsigned int lds_u32;
typedef __attribute__((address_space(1))) const unsigned int glb_u32;

__device__ __forceinline__ void dma16(const void* g, void* l) {
    // per-lane GLOBAL src; wave-uniform LDS base, HW writes lane i at base+i*16.
    __builtin_amdgcn_global_load_lds((glb_u32*)g, (lds_u32*)l, 16, 0, 0);
}

__device__ __forceinline__ unsigned short f2bf(float f) {
    unsigned u = __builtin_bit_cast(unsigned, f);
    u += 0x7FFFu + ((u >> 16) & 1u);   // round-to-nearest-even
    return (unsigned short)(u >> 16);
}
__device__ __forceinline__ float bf2f(unsigned short h) {
    unsigned u = ((unsigned)h) << 16;
    return __builtin_bit_cast(float, u);
}

__device__ __forceinline__ f32x4 mfma16(s16x8 a, s16x8 b, f32x4 c) {
    return __builtin_amdgcn_mfma_f32_16x16x32_bf16(a, b, c, 0, 0, 0);
}

// ---------------------------------------------------------------- edge dtype
__global__ void detect_kernel(const unsigned int* __restrict__ E, int* flag) {
    int lane = threadIdx.x;
    unsigned v = E[2 * lane + 1];
    unsigned long long m = __ballot(v == 0u);
    if (lane == 0) *flag = (__popcll(m) >= 48) ? 1 : 0;
}

__device__ __forceinline__ int edge_at(const void* E, int idx, int is64) {
    return is64 ? (int)((const long long*)E)[idx] : ((const int*)E)[idx];
}

// ---------------------------------------------------------------- CSR build
__global__ __launch_bounds__(256) void deg_cnt_kernel(const void* __restrict__ E,
                                                      const int* __restrict__ flag,
                                                      int* deg, int* cnt) {
    int e = blockIdx.x * 256 + threadIdx.x;
    if (e >= NEDGE) return;
    int is64 = *flag;
    int s = edge_at(E, e, is64);
    int d = edge_at(E, e + NEDGE, is64);
    if (s != d) {
        atomicAdd(&deg[s], 1);
        atomicAdd(&cnt[d], 1);
    }
}

__global__ __launch_bounds__(256) void dinv_kernel(const int* __restrict__ deg,
                                                   float* __restrict__ dinv) {
    int i = blockIdx.x * 256 + threadIdx.x;
    if (i < NSEG) {
        int d = deg[i];
        dinv[i] = d > 0 ? rsqrtf((float)d) : 0.f;
    }
}

// --- hierarchical scan
__global__ __launch_bounds__(256) void scan1_kernel(const int* __restrict__ cnt,
                                                    int* __restrict__ bsum) {
    __shared__ int sh[256];
    int t = threadIdx.x;
    int i = blockIdx.x * 256 + t;
    sh[t] = (i < NSEG) ? cnt[i] : 0;
    __syncthreads();
    for (int o = 128; o > 0; o >>= 1) {
        if (t < o) sh[t] += sh[t + o];
        __syncthreads();
    }
    if (t == 0) bsum[blockIdx.x] = sh[0];
}

__global__ __launch_bounds__(256) void scan2_kernel(const int* __restrict__ bsum,
                                                    int* __restrict__ boff,
                                                    int* __restrict__ rowptr) {
    __shared__ int sh[256];
    int t = threadIdx.x;
    int v = (t < NBLK) ? bsum[t] : 0;
    sh[t] = v;
    __syncthreads();
    for (int o = 1; o < 256; o <<= 1) {
        int x = 0;
        if (t >= o) x = sh[t - o];
        __syncthreads();
        if (t >= o) sh[t] += x;
        __syncthreads();
    }
    if (t < NBLK) boff[t] = sh[t] - v;
    if (t == 255) rowptr[NSEG] = sh[255];
}

__global__ __launch_bounds__(256) void scan3_kernel(const int* __restrict__ cnt,
                                                    const int* __restrict__ boff,
                                                    int* __restrict__ rowptr,
                                                    int* __restrict__ cursor) {
    __shared__ int sh[256];
    int t = threadIdx.x;
    int i = blockIdx.x * 256 + t;
    int v = (i < NSEG) ? cnt[i] : 0;
    sh[t] = v;
    __syncthreads();
    for (int o = 1; o < 256; o <<= 1) {
        int x = 0;
        if (t >= o) x = sh[t - o];
        __syncthreads();
        if (t >= o) sh[t] += x;
        __syncthreads();
    }
    if (i < NSEG) {
        int p = boff[blockIdx.x] + sh[t] - v;
        rowptr[i] = p;
        cursor[i] = p;
    }
}

__global__ __launch_bounds__(256) void scatter_kernel(const void* __restrict__ E,
                                                      const int* __restrict__ flag,
                                                      const float* __restrict__ dinv,
                                                      int* cursor,
                                                      int* __restrict__ colidx,
                                                      float* __restrict__ val) {
    int e = blockIdx.x * 256 + threadIdx.x;
    if (e >= NEDGE) return;
    int is64 = *flag;
    int s = edge_at(E, e, is64);
    int d = edge_at(E, e + NEDGE, is64);
    if (s != d) {
        int pos = atomicAdd(&cursor[d], 1);
        colidx[pos] = s;
        val[pos] = -dinv[s] * dinv[d];
    }
}

// ---------------------------------------------------------------- weight prep
__global__ void prep_pt_kernel(const float* __restrict__ P, unsigned short* __restrict__ Pt) {
    int n = blockIdx.x;
    for (int k = threadIdx.x; k < KP1; k += blockDim.x)
        Pt[(size_t)n * KP1 + k] = (k < NREG) ? f2bf(P[(size_t)k * HID + n]) : (unsigned short)0;
}
__global__ void prep_wt_kernel(const float* __restrict__ W, unsigned short* __restrict__ Wt) {
    int n = blockIdx.x;
    for (int k = threadIdx.x; k < KCAT; k += blockDim.x)
        Wt[(size_t)n * KCAT + k] = f2bf(W[(size_t)k * HID + n]);
}

// ---------------------------------------------------------------- GEMM1 (concurrency regime)
// raw = S @ P ; bf16 copy into Xcat seg 0.
// BM=32 BN=256 BK=32, 256 thr = 4 waves (each a 32x64 tile), grid 1250.
// Single-buffered 18KB LDS -> 8 blocks/CU capacity; TLP (not intra-wave
// pipelining) hides latency — the R1-measured regime (2.26 TB/s @ 64% occ).
__global__ __launch_bounds__(256) void gemm1_kernel(const float* __restrict__ S,
                                                    const unsigned short* __restrict__ Pt,
                                                    float* __restrict__ raw,
                                                    unsigned short* __restrict__ xcat) {
    __shared__ unsigned short As[32 * 32];
    __shared__ unsigned short Bs[256 * 32];
    const int tid = threadIdx.x;
    const int lane = tid & 63, wn = tid >> 6;
    const int r = lane & 15, q = lane >> 4;
    const int qx8 = (q ^ (r & 3)) << 3;               // read-side of granule involution
    const int m0 = blockIdx.x * 32;                    // 40000 % 32 == 0
    const int arow = tid >> 3, acol = (tid & 7) * 4;   // 8 thr/row x 4 floats = 32 k
    const int agr = ((((acol >> 3) ^ (arow & 3)) << 3) | (acol & 7));  // swizzled elem col
    const int crow = lane >> 2;
    const int bcol = (((lane & 3) ^ (crow & 3)) << 3); // dma src granule (pre-swizzled)
    const float* aptr = S + (size_t)(m0 + arow) * NREG;

    f32x4 acc[2][4] = {};

    for (int t = 0; t < 32; ++t) {
        const int kb = t * 32;
        __syncthreads();   // readers of previous tile done
        // stage B: 16 chunks of 1KB, 4 per wave
#pragma unroll
        for (int k = 0; k < 4; ++k) {
            int j = wn * 4 + k;
            dma16(Pt + (size_t)(j * 16 + crow) * KP1 + kb + bcol, &Bs[j * 512]);
        }
        // stage A: fp32 -> bf16, swizzled ds_write
        {
            int k0 = kb + acol;
            if (k0 + 4 > NREG) k0 = 0;   // tail: garbage x B-pad-zeros = 0
            f32x4 v = *(const f32x4*)(aptr + k0);
            u16x4 o = {f2bf(v[0]), f2bf(v[1]), f2bf(v[2]), f2bf(v[3])};
            *(u16x4*)&As[arow * 32 + agr] = o;
        }
        __syncthreads();   // drains dma (vmcnt) + ds_write (lgkm)
        s16x8 af[2], bfv[4];
#pragma unroll
        for (int am = 0; am < 2; ++am)
            af[am] = *(const s16x8*)&As[(am * 16 + r) * 32 + qx8];
#pragma unroll
        for (int bn = 0; bn < 4; ++bn)
            bfv[bn] = *(const s16x8*)&Bs[(wn * 64 + bn * 16 + r) * 32 + qx8];
#pragma unroll
        for (int am = 0; am < 2; ++am)
#pragma unroll
            for (int bn = 0; bn < 4; ++bn)
                acc[am][bn] = mfma16(af[am], bfv[bn], acc[am][bn]);
    }

#pragma unroll
    for (int am = 0; am < 2; ++am) {
        int rowb = m0 + am * 16 + q * 4;
#pragma unroll
        for (int bn = 0; bn < 4; ++bn) {
            int col = wn * 64 + bn * 16 + r;
#pragma unroll
            for (int i = 0; i < 4; ++i) {
                float v = acc[am][bn][i];
                raw[(size_t)(rowb + i) * HID + col] = v;
                xcat[(size_t)(rowb + i) * KCAT + col] = f2bf(v);
            }
        }
    }
}

// ---------------------------------------------------------------- propagation
__global__ __launch_bounds__(256) void prop_kernel(unsigned short* xcat,
                                                   const int* __restrict__ rowptr,
                                                   const int* __restrict__ colidx,
                                                   const float* __restrict__ val,
                                                   int inOff, int outOff, int subOff,
                                                   float scale) {
    int g = blockIdx.x * 4 + (threadIdx.x >> 6);
    int lane = threadIdx.x & 63;
    int e0 = rowptr[g], e1 = rowptr[g + 1];
    float a0 = 0.f, a1 = 0.f, a2 = 0.f, a3 = 0.f;
    const unsigned short* xin = xcat + inOff + lane * 4;
    for (int base = e0; base < e1; base += 64) {
        int m = e1 - base;
        if (m > 64) m = 64;
        int cc = 0;
        float vv = 0.f;
        if (lane < m) {
            cc = colidx[base + lane];
            vv = val[base + lane];
        }
        int i = 0;
        for (; i + 8 <= m; i += 8) {
            u16x4 t[8];
#pragma unroll
            for (int j = 0; j < 8; ++j) {
                int c = __shfl(cc, i + j);
                t[j] = *(const u16x4*)(xin + (size_t)c * KCAT);
            }
#pragma unroll
            for (int j = 0; j < 8; ++j) {
                float v = __shfl(vv, i + j);
                a0 += v * bf2f(t[j][0]);
                a1 += v * bf2f(t[j][1]);
                a2 += v * bf2f(t[j][2]);
                a3 += v * bf2f(t[j][3]);
            }
        }
        for (; i < m; ++i) {
            int c = __shfl(cc, i);
            float v = __shfl(vv, i);
            u16x4 t = *(const u16x4*)(xin + (size_t)c * KCAT);
            a0 += v * bf2f(t[0]);
            a1 += v * bf2f(t[1]);
            a2 += v * bf2f(t[2]);
            a3 += v * bf2f(t[3]);
        }
    }
    a0 *= scale; a1 *= scale; a2 *= scale; a3 *= scale;
    if (subOff >= 0) {
        u16x4 p = *(const u16x4*)(xcat + (size_t)g * KCAT + subOff + lane * 4);
        a0 -= bf2f(p[0]); a1 -= bf2f(p[1]); a2 -= bf2f(p[2]); a3 -= bf2f(p[3]);
    }
    u16x4 o = {f2bf(a0), f2bf(a1), f2bf(a2), f2bf(a3)};
    *(u16x4*)(xcat + (size_t)g * KCAT + outOff + lane * 4) = o;
}

// ---------------------------------------------------------------- GEMM2 + GELU + LN (concurrency regime)
// BM=32 BN=256 BK=32, 256 thr, single-buffer, A+B both via global_load_lds.
__global__ __launch_bounds__(256) void gemm2_kernel(const unsigned short* __restrict__ xcat,
                                                    const unsigned short* __restrict__ Wt,
                                                    const float* __restrict__ bias,
                                                    const float* __restrict__ gamma,
                                                    const float* __restrict__ beta,
                                                    float* __restrict__ outp) {
    __shared__ unsigned short As[32 * 32];
    __shared__ unsigned short Bs[256 * 32];
    __shared__ float rs[32][4];
    __shared__ float rss[32][4];
    const int tid = threadIdx.x;
    const int lane = tid & 63, wn = tid >> 6;
    const int r = lane & 15, q = lane >> 4;
    const int qx8 = (q ^ (r & 3)) << 3;
    const int m0 = blockIdx.x * 32;
    const int crow = lane >> 2;
    const int bcol = (((lane & 3) ^ (crow & 3)) << 3);

    f32x4 acc[2][4] = {};

    for (int t = 0; t < 40; ++t) {
        const int kb = t * 32;
        __syncthreads();
#pragma unroll
        for (int k = 0; k < 4; ++k) {
            int j = wn * 4 + k;
            dma16(Wt + (size_t)(j * 16 + crow) * KCAT + kb + bcol, &Bs[j * 512]);
        }
        if (wn < 2) {
            int row = m0 + wn * 16 + crow;
            dma16(xcat + (size_t)row * KCAT + kb + bcol, &As[wn * 512]);
        }
        __syncthreads();
        s16x8 af[2], bfv[4];
#pragma unroll
        for (int am = 0; am < 2; ++am)
            af[am] = *(const s16x8*)&As[(am * 16 + r) * 32 + qx8];
#pragma unroll
        for (int bn = 0; bn < 4; ++bn)
            bfv[bn] = *(const s16x8*)&Bs[(wn * 64 + bn * 16 + r) * 32 + qx8];
#pragma unroll
        for (int am = 0; am < 2; ++am)
#pragma unroll
            for (int bn = 0; bn < 4; ++bn)
                acc[am][bn] = mfma16(af[am], bfv[bn], acc[am][bn]);
    }

    // epilogue: bias + exact GELU, row stats, LN, store
    float bc[4], gm[4], bt[4];
#pragma unroll
    for (int bn = 0; bn < 4; ++bn) {
        int col = wn * 64 + bn * 16 + r;
        bc[bn] = bias[col];
        gm[bn] = gamma[col];
        bt[bn] = beta[col];
    }
#pragma unroll
    for (int am = 0; am < 2; ++am) {
#pragma unroll
        for (int i = 0; i < 4; ++i) {
            float s = 0.f, ss = 0.f;
#pragma unroll
            for (int bn = 0; bn < 4; ++bn) {
                float v = acc[am][bn][i] + bc[bn];
                v = 0.5f * v * (1.f + erff(v * 0.70710678118654752f));
                acc[am][bn][i] = v;
                s += v;
                ss += v * v;
            }
#pragma unroll
            for (int msk = 1; msk < 16; msk <<= 1) {
                s += __shfl_xor(s, msk);
                ss += __shfl_xor(ss, msk);
            }
            if (r == 0) {
                int row = am * 16 + q * 4 + i;
                rs[row][wn] = s;
                rss[row][wn] = ss;
            }
        }
    }
    __syncthreads();
#pragma unroll
    for (int am = 0; am < 2; ++am) {
#pragma unroll
        for (int i = 0; i < 4; ++i) {
            int row = am * 16 + q * 4 + i;
            float s = rs[row][0] + rs[row][1] + rs[row][2] + rs[row][3];
            float ss = rss[row][0] + rss[row][1] + rss[row][2] + rss[row][3];
            float mu = s * (1.f / HID);
            float var = ss * (1.f / HID) - mu * mu;
            float inv = rsqrtf(var + 1e-5f);
#pragma unroll
            for (int bn = 0; bn < 4; ++bn) {
                int col = wn * 64 + bn * 16 + r;
                outp[(size_t)(m0 + row) * HID + col] = (acc[am][bn][i] - mu) * inv * gm[bn] + bt[bn];
            }
        }
    }
}

// ---------------------------------------------------------------- launch
extern "C" void kernel_launch(void* const* d_in, const int* in_sizes, int n_in,
                              void* d_out, int out_size, void* d_ws, size_t ws_size,
                              hipStream_t stream) {
    const float* P     = (const float*)d_in[0];
    const float* S     = (const float*)d_in[1];
    const void*  E     = d_in[2];
    const float* W     = (const float*)d_in[3];
    const float* bias  = (const float*)d_in[4];
    const float* gamma = (const float*)d_in[5];
    const float* beta  = (const float*)d_in[6];

    float* out = (float*)d_out;            // seg_low [40000*256]
    float* raw = out + (size_t)NSEG * HID; // seg_low_raw [40000*256]

    char* ws = (char*)d_ws;
    size_t off = 0;
    auto alloc = [&](size_t bytes) -> void* {
        void* p = ws + off;
        off += (bytes + 255) & ~(size_t)255;
        return p;
    };
    unsigned short* xcat   = (unsigned short*)alloc((size_t)NSEG * KCAT * 2);
    unsigned short* Pt     = (unsigned short*)alloc((size_t)HID * KP1 * 2);
    unsigned short* Wt     = (unsigned short*)alloc((size_t)HID * KCAT * 2);
    int*            deg    = (int*)alloc((size_t)NSEG * 4);
    float*          dinv   = (float*)alloc((size_t)NSEG * 4);
    int*            cnt    = (int*)alloc((size_t)NSEG * 4);
    int*            rowptr = (int*)alloc((size_t)(NSEG + 1) * 4);
    int*            cursor = (int*)alloc((size_t)NSEG * 4);
    int*            colidx = (int*)alloc((size_t)NEDGE * 4);
    float*          val    = (float*)alloc((size_t)NEDGE * 4);
    int*            bsum   = (int*)alloc((size_t)NBLK * 4);
    int*            boff   = (int*)alloc((size_t)NBLK * 4);
    int*            flag   = (int*)alloc(256);
    if (off > ws_size) return;

    hipMemsetAsync(deg, 0, (size_t)NSEG * 4, stream);
    hipMemsetAsync(cnt, 0, (size_t)NSEG * 4, stream);

    detect_kernel<<<1, 64, 0, stream>>>((const unsigned int*)E, flag);
    prep_pt_kernel<<<HID, 256, 0, stream>>>(P, Pt);
    prep_wt_kernel<<<HID, 256, 0, stream>>>(W, Wt);

    deg_cnt_kernel<<<NEDGE / 256, 256, 0, stream>>>(E, flag, deg, cnt);
    dinv_kernel<<<(NSEG + 255) / 256, 256, 0, stream>>>(deg, dinv);
    scan1_kernel<<<NBLK, 256, 0, stream>>>(cnt, bsum);
    scan2_kernel<<<1, 256, 0, stream>>>(bsum, boff, rowptr);
    scan3_kernel<<<NBLK, 256, 0, stream>>>(cnt, boff, rowptr, cursor);
    scatter_kernel<<<NEDGE / 256, 256, 0, stream>>>(E, flag, dinv, cursor, colidx, val);

    gemm1_kernel<<<NSEG / 32, 256, 0, stream>>>(S, Pt, raw, xcat);

    prop_kernel<<<NSEG / 4, 256, 0, stream>>>(xcat, rowptr, colidx, val, 0 * HID, 1 * HID, -1, 1.f);
    prop_kernel<<<NSEG / 4, 256, 0, stream>>>(xcat, rowptr, colidx, val, 1 * HID, 2 * HID, 0 * HID, 2.f);
    prop_kernel<<<NSEG / 4, 256, 0, stream>>>(xcat, rowptr, colidx, val, 2 * HID, 3 * HID, 1 * HID, 2.f);
    prop_kernel<<<NSEG / 4, 256, 0, stream>>>(xcat, rowptr, colidx, val, 3 * HID, 4 * HID, 2 * HID, 2.f);

    gemm2_kernel<<<NSEG / 32, 256, 0, stream>>>(xcat, Wt, bias, gamma, beta, out);
}

// Round 9
// 436.825 us; speedup vs baseline: 1.1262x; 1.1262x over previous
//
#include <hip/hip_runtime.h>

#define NSEG 40000
#define NREG 1000
#define NEDGE 640000
#define HID 256
#define KCAT 1280   // 5 * HID
#define KP1 1024    // padded K stride for Pt (cols 1000..1023 zero)
#define LPAD 40     // LDS row stride (bf16) for gemm1 tiles
#define NBLK 157    // ceil(NSEG/256)

typedef float f32x4 __attribute__((ext_vector_type(4)));
typedef short s16x8 __attribute__((ext_vector_type(8)));
typedef unsigned short u16x4 __attribute__((ext_vector_type(4)));
typedef unsigned short u16x8 __attribute__((ext_vector_type(8)));

typedef __attribute__((address_space(3))) unsigned int lds_u32;
typedef __attribute__((address_space(1))) const unsigned int glb_u32;

__device__ __forceinline__ void dma16(const void* g, void* l) {
    // per-lane GLOBAL src; wave-uniform LDS base, HW writes lane i at base+i*16.
    __builtin_amdgcn_global_load_lds((glb_u32*)g, (lds_u32*)l, 16, 0, 0);
}

__device__ __forceinline__ unsigned short f2bf(float f) {
    unsigned u = __builtin_bit_cast(unsigned, f);
    u += 0x7FFFu + ((u >> 16) & 1u);   // round-to-nearest-even
    return (unsigned short)(u >> 16);
}
__device__ __forceinline__ float bf2f(unsigned short h) {
    unsigned u = ((unsigned)h) << 16;
    return __builtin_bit_cast(float, u);
}

__device__ __forceinline__ f32x4 mfma16(s16x8 a, s16x8 b, f32x4 c) {
    return __builtin_amdgcn_mfma_f32_16x16x32_bf16(a, b, c, 0, 0, 0);
}

// ---------------------------------------------------------------- edge dtype
__global__ void detect_kernel(const unsigned int* __restrict__ E, int* flag) {
    int lane = threadIdx.x;
    unsigned v = E[2 * lane + 1];
    unsigned long long m = __ballot(v == 0u);
    if (lane == 0) *flag = (__popcll(m) >= 48) ? 1 : 0;
}

__device__ __forceinline__ int edge_at(const void* E, int idx, int is64) {
    return is64 ? (int)((const long long*)E)[idx] : ((const int*)E)[idx];
}

// ---------------------------------------------------------------- CSR build
__global__ __launch_bounds__(256) void deg_cnt_kernel(const void* __restrict__ E,
                                                      const int* __restrict__ flag,
                                                      int* deg, int* cnt) {
    int e = blockIdx.x * 256 + threadIdx.x;
    if (e >= NEDGE) return;
    int is64 = *flag;
    int s = edge_at(E, e, is64);
    int d = edge_at(E, e + NEDGE, is64);
    if (s != d) {
        atomicAdd(&deg[s], 1);
        atomicAdd(&cnt[d], 1);
    }
}

__global__ __launch_bounds__(256) void dinv_kernel(const int* __restrict__ deg,
                                                   float* __restrict__ dinv) {
    int i = blockIdx.x * 256 + threadIdx.x;
    if (i < NSEG) {
        int d = deg[i];
        dinv[i] = d > 0 ? rsqrtf((float)d) : 0.f;
    }
}

// --- hierarchical scan
__global__ __launch_bounds__(256) void scan1_kernel(const int* __restrict__ cnt,
                                                    int* __restrict__ bsum) {
    __shared__ int sh[256];
    int t = threadIdx.x;
    int i = blockIdx.x * 256 + t;
    sh[t] = (i < NSEG) ? cnt[i] : 0;
    __syncthreads();
    for (int o = 128; o > 0; o >>= 1) {
        if (t < o) sh[t] += sh[t + o];
        __syncthreads();
    }
    if (t == 0) bsum[blockIdx.x] = sh[0];
}

__global__ __launch_bounds__(256) void scan2_kernel(const int* __restrict__ bsum,
                                                    int* __restrict__ boff,
                                                    int* __restrict__ rowptr) {
    __shared__ int sh[256];
    int t = threadIdx.x;
    int v = (t < NBLK) ? bsum[t] : 0;
    sh[t] = v;
    __syncthreads();
    for (int o = 1; o < 256; o <<= 1) {
        int x = 0;
        if (t >= o) x = sh[t - o];
        __syncthreads();
        if (t >= o) sh[t] += x;
        __syncthreads();
    }
    if (t < NBLK) boff[t] = sh[t] - v;
    if (t == 255) rowptr[NSEG] = sh[255];
}

__global__ __launch_bounds__(256) void scan3_kernel(const int* __restrict__ cnt,
                                                    const int* __restrict__ boff,
                                                    int* __restrict__ rowptr,
                                                    int* __restrict__ cursor) {
    __shared__ int sh[256];
    int t = threadIdx.x;
    int i = blockIdx.x * 256 + t;
    int v = (i < NSEG) ? cnt[i] : 0;
    sh[t] = v;
    __syncthreads();
    for (int o = 1; o < 256; o <<= 1) {
        int x = 0;
        if (t >= o) x = sh[t - o];
        __syncthreads();
        if (t >= o) sh[t] += x;
        __syncthreads();
    }
    if (i < NSEG) {
        int p = boff[blockIdx.x] + sh[t] - v;
        rowptr[i] = p;
        cursor[i] = p;
    }
}

__global__ __launch_bounds__(256) void scatter_kernel(const void* __restrict__ E,
                                                      const int* __restrict__ flag,
                                                      const float* __restrict__ dinv,
                                                      int* cursor,
                                                      int* __restrict__ colidx,
                                                      float* __restrict__ val) {
    int e = blockIdx.x * 256 + threadIdx.x;
    if (e >= NEDGE) return;
    int is64 = *flag;
    int s = edge_at(E, e, is64);
    int d = edge_at(E, e + NEDGE, is64);
    if (s != d) {
        int pos = atomicAdd(&cursor[d], 1);
        colidx[pos] = s;
        val[pos] = -dinv[s] * dinv[d];
    }
}

// ---------------------------------------------------------------- weight prep
__global__ void prep_pt_kernel(const float* __restrict__ P, unsigned short* __restrict__ Pt) {
    int n = blockIdx.x;
    for (int k = threadIdx.x; k < KP1; k += blockDim.x)
        Pt[(size_t)n * KP1 + k] = (k < NREG) ? f2bf(P[(size_t)k * HID + n]) : (unsigned short)0;
}
__global__ void prep_wt_kernel(const float* __restrict__ W, unsigned short* __restrict__ Wt) {
    int n = blockIdx.x;
    for (int k = threadIdx.x; k < KCAT; k += blockDim.x)
        Wt[(size_t)n * KCAT + k] = f2bf(W[(size_t)k * HID + n]);
}

// ---------------------------------------------------------------- GEMM1 (R3-exact, best measured: 106.8us)
// raw = S @ P ; bf16 copy into Xcat seg 0.  BM=64 BN=256 BK=32, 256 thr,
// 2-barrier loop, plain vector loads -> padded LDS (no DMA).
__global__ __launch_bounds__(256) void gemm1_kernel(const float* __restrict__ S,
                                                    const unsigned short* __restrict__ Pt,
                                                    float* __restrict__ raw,
                                                    unsigned short* __restrict__ xcat) {
    __shared__ unsigned short As[64][LPAD];
    __shared__ unsigned short Bs[256][LPAD];
    const int m0 = blockIdx.x * 64;
    const int tid = threadIdx.x;
    const int lane = tid & 63, wn = tid >> 6;
    const int r = lane & 15, q = lane >> 4;
    const int srow = tid >> 2, scol = (tid & 3) * 8;

    f32x4 acc[4][4] = {};

    for (int kb = 0; kb < NREG; kb += 32) {
        const bool kvalid = (kb + scol + 8 <= NREG);  // NREG % 8 == 0
        u16x8 av = {0, 0, 0, 0, 0, 0, 0, 0};
        u16x8 bv0 = av, bv1 = av, bv2 = av, bv3 = av;
        if (kvalid) {
            const float* sp = S + (size_t)(m0 + srow) * NREG + kb + scol;
            f32x4 f0 = *(const f32x4*)sp;
            f32x4 f1 = *(const f32x4*)(sp + 4);
            av[0] = f2bf(f0[0]); av[1] = f2bf(f0[1]); av[2] = f2bf(f0[2]); av[3] = f2bf(f0[3]);
            av[4] = f2bf(f1[0]); av[5] = f2bf(f1[1]); av[6] = f2bf(f1[2]); av[7] = f2bf(f1[3]);
            bv0 = *(const u16x8*)(Pt + (size_t)(srow)       * KP1 + kb + scol);
            bv1 = *(const u16x8*)(Pt + (size_t)(srow +  64) * KP1 + kb + scol);
            bv2 = *(const u16x8*)(Pt + (size_t)(srow + 128) * KP1 + kb + scol);
            bv3 = *(const u16x8*)(Pt + (size_t)(srow + 192) * KP1 + kb + scol);
        }
        __syncthreads();
        *(u16x8*)&As[srow][scol] = av;
        *(u16x8*)&Bs[srow][scol] = bv0;
        *(u16x8*)&Bs[srow + 64][scol] = bv1;
        *(u16x8*)&Bs[srow + 128][scol] = bv2;
        *(u16x8*)&Bs[srow + 192][scol] = bv3;
        __syncthreads();
        s16x8 af[4], bfv[4];
#pragma unroll
        for (int am = 0; am < 4; ++am) af[am] = *(const s16x8*)&As[am * 16 + r][q * 8];
#pragma unroll
        for (int bn = 0; bn < 4; ++bn) bfv[bn] = *(const s16x8*)&Bs[wn * 64 + bn * 16 + r][q * 8];
#pragma unroll
        for (int am = 0; am < 4; ++am) {
#pragma unroll
            for (int bn = 0; bn < 4; ++bn)
                acc[am][bn] = mfma16(af[am], bfv[bn], acc[am][bn]);
        }
    }
#pragma unroll
    for (int am = 0; am < 4; ++am) {
        int rowb = m0 + am * 16 + q * 4;
#pragma unroll
        for (int bn = 0; bn < 4; ++bn) {
            int col = wn * 64 + bn * 16 + r;
#pragma unroll
            for (int i = 0; i < 4; ++i) {
                float v = acc[am][bn][i];
                raw[(size_t)(rowb + i) * HID + col] = v;
                xcat[(size_t)(rowb + i) * KCAT + col] = f2bf(v);
            }
        }
    }
}

// ---------------------------------------------------------------- propagation
__global__ __launch_bounds__(256) void prop_kernel(unsigned short* xcat,
                                                   const int* __restrict__ rowptr,
                                                   const int* __restrict__ colidx,
                                                   const float* __restrict__ val,
                                                   int inOff, int outOff, int subOff,
                                                   float scale) {
    int g = blockIdx.x * 4 + (threadIdx.x >> 6);
    int lane = threadIdx.x & 63;
    int e0 = rowptr[g], e1 = rowptr[g + 1];
    float a0 = 0.f, a1 = 0.f, a2 = 0.f, a3 = 0.f;
    const unsigned short* xin = xcat + inOff + lane * 4;
    for (int base = e0; base < e1; base += 64) {
        int m = e1 - base;
        if (m > 64) m = 64;
        int cc = 0;
        float vv = 0.f;
        if (lane < m) {
            cc = colidx[base + lane];
            vv = val[base + lane];
        }
        int i = 0;
        for (; i + 8 <= m; i += 8) {
            u16x4 t[8];
#pragma unroll
            for (int j = 0; j < 8; ++j) {
                int c = __shfl(cc, i + j);
                t[j] = *(const u16x4*)(xin + (size_t)c * KCAT);
            }
#pragma unroll
            for (int j = 0; j < 8; ++j) {
                float v = __shfl(vv, i + j);
                a0 += v * bf2f(t[j][0]);
                a1 += v * bf2f(t[j][1]);
                a2 += v * bf2f(t[j][2]);
                a3 += v * bf2f(t[j][3]);
            }
        }
        for (; i < m; ++i) {
            int c = __shfl(cc, i);
            float v = __shfl(vv, i);
            u16x4 t = *(const u16x4*)(xin + (size_t)c * KCAT);
            a0 += v * bf2f(t[0]);
            a1 += v * bf2f(t[1]);
            a2 += v * bf2f(t[2]);
            a3 += v * bf2f(t[3]);
        }
    }
    a0 *= scale; a1 *= scale; a2 *= scale; a3 *= scale;
    if (subOff >= 0) {
        u16x4 p = *(const u16x4*)(xcat + (size_t)g * KCAT + subOff + lane * 4);
        a0 -= bf2f(p[0]); a1 -= bf2f(p[1]); a2 -= bf2f(p[2]); a3 -= bf2f(p[3]);
    }
    u16x4 o = {f2bf(a0), f2bf(a1), f2bf(a2), f2bf(a3)};
    *(u16x4*)(xcat + (size_t)g * KCAT + outOff + lane * 4) = o;
}

// ---------------------------------------------------------------- GEMM2 + GELU + LN (R6-exact, BM=128 dbuf-DMA)
__global__ __launch_bounds__(512) void gemm2_kernel(const unsigned short* __restrict__ xcat,
                                                    const unsigned short* __restrict__ Wt,
                                                    const float* __restrict__ bias,
                                                    const float* __restrict__ gamma,
                                                    const float* __restrict__ beta,
                                                    float* __restrict__ outp) {
    __shared__ unsigned short As[2][128 * 32];
    __shared__ unsigned short Bs[2][256 * 32];
    __shared__ float rs[128][4];
    __shared__ float rss[128][4];
    const int tid = threadIdx.x;
    const int lane = tid & 63, wid = tid >> 6;
    const int wm = wid >> 2, wn = wid & 3;
    const int r = lane & 15, q = lane >> 4;
    const int qx8 = (q ^ (r & 3)) << 3;
    const int m0 = blockIdx.x * 128;
    const int crow = lane >> 2;
    const int bcol = (((lane & 3) ^ ((lane >> 2) & 3)) << 3);

    f32x4 acc[4][4] = {};

    // 24 chunks/buffer: 0..15 = B (Wt rows), 16..23 = A (xcat rows m0+..).
    auto stage = [&](int c, int kb) {
#pragma unroll
        for (int k = 0; k < 3; ++k) {
            int idx = 3 * wid + k;
            if (idx < 16) {
                int n = idx * 16 + crow;
                dma16(Wt + (size_t)n * KCAT + kb + bcol, &Bs[c][idx * 512]);
            } else {
                int a = idx - 16;
                int row = m0 + a * 16 + crow;   // tail reads past xcat land in Pt region: safe, store-guarded
                dma16(xcat + (size_t)row * KCAT + kb + bcol, &As[c][a * 512]);
            }
        }
    };

    stage(0, 0);
    __syncthreads();

    for (int t = 0; t < 40; ++t) {
        const int c = t & 1;
        if (t < 39) stage(c ^ 1, (t + 1) * 32);
        s16x8 af[4], bfv[4];
#pragma unroll
        for (int am = 0; am < 4; ++am)
            af[am] = *(const s16x8*)&As[c][(wm * 64 + am * 16 + r) * 32 + qx8];
#pragma unroll
        for (int bn = 0; bn < 4; ++bn)
            bfv[bn] = *(const s16x8*)&Bs[c][(wn * 64 + bn * 16 + r) * 32 + qx8];
#pragma unroll
        for (int am = 0; am < 4; ++am)
#pragma unroll
            for (int bn = 0; bn < 4; ++bn)
                acc[am][bn] = mfma16(af[am], bfv[bn], acc[am][bn]);
        __syncthreads();
    }

    // epilogue: bias + exact GELU, row stats, LN, store
    float bc[4], gm[4], bt[4];
#pragma unroll
    for (int bn = 0; bn < 4; ++bn) {
        int col = wn * 64 + bn * 16 + r;
        bc[bn] = bias[col];
        gm[bn] = gamma[col];
        bt[bn] = beta[col];
    }
#pragma unroll
    for (int am = 0; am < 4; ++am) {
#pragma unroll
        for (int i = 0; i < 4; ++i) {
            float s = 0.f, ss = 0.f;
#pragma unroll
            for (int bn = 0; bn < 4; ++bn) {
                float v = acc[am][bn][i] + bc[bn];
                v = 0.5f * v * (1.f + erff(v * 0.70710678118654752f));
                acc[am][bn][i] = v;
                s += v;
                ss += v * v;
            }
#pragma unroll
            for (int msk = 1; msk < 16; msk <<= 1) {
                s += __shfl_xor(s, msk);
                ss += __shfl_xor(ss, msk);
            }
            if (r == 0) {
                int row = wm * 64 + am * 16 + q * 4 + i;
                rs[row][wn] = s;
                rss[row][wn] = ss;
            }
        }
    }
    __syncthreads();
#pragma unroll
    for (int am = 0; am < 4; ++am) {
#pragma unroll
        for (int i = 0; i < 4; ++i) {
            int row = wm * 64 + am * 16 + q * 4 + i;
            float s = rs[row][0] + rs[row][1] + rs[row][2] + rs[row][3];
            float ss = rss[row][0] + rss[row][1] + rss[row][2] + rss[row][3];
            float mu = s * (1.f / HID);
            float var = ss * (1.f / HID) - mu * mu;
            float inv = rsqrtf(var + 1e-5f);
            if (m0 + row < NSEG) {
#pragma unroll
                for (int bn = 0; bn < 4; ++bn) {
                    int col = wn * 64 + bn * 16 + r;
                    outp[(size_t)(m0 + row) * HID + col] = (acc[am][bn][i] - mu) * inv * gm[bn] + bt[bn];
                }
            }
        }
    }
}

// ---------------------------------------------------------------- launch
extern "C" void kernel_launch(void* const* d_in, const int* in_sizes, int n_in,
                              void* d_out, int out_size, void* d_ws, size_t ws_size,
                              hipStream_t stream) {
    const float* P     = (const float*)d_in[0];
    const float* S     = (const float*)d_in[1];
    const void*  E     = d_in[2];
    const float* W     = (const float*)d_in[3];
    const float* bias  = (const float*)d_in[4];
    const float* gamma = (const float*)d_in[5];
    const float* beta  = (const float*)d_in[6];

    float* out = (float*)d_out;            // seg_low [40000*256]
    float* raw = out + (size_t)NSEG * HID; // seg_low_raw [40000*256]

    char* ws = (char*)d_ws;
    size_t off = 0;
    auto alloc = [&](size_t bytes) -> void* {
        void* p = ws + off;
        off += (bytes + 255) & ~(size_t)255;
        return p;
    };
    unsigned short* xcat   = (unsigned short*)alloc((size_t)NSEG * KCAT * 2);
    unsigned short* Pt     = (unsigned short*)alloc((size_t)HID * KP1 * 2);
    unsigned short* Wt     = (unsigned short*)alloc((size_t)HID * KCAT * 2);
    int*            deg    = (int*)alloc((size_t)NSEG * 4);
    float*          dinv   = (float*)alloc((size_t)NSEG * 4);
    int*            cnt    = (int*)alloc((size_t)NSEG * 4);
    int*            rowptr = (int*)alloc((size_t)(NSEG + 1) * 4);
    int*            cursor = (int*)alloc((size_t)NSEG * 4);
    int*            colidx = (int*)alloc((size_t)NEDGE * 4);
    float*          val    = (float*)alloc((size_t)NEDGE * 4);
    int*            bsum   = (int*)alloc((size_t)NBLK * 4);
    int*            boff   = (int*)alloc((size_t)NBLK * 4);
    int*            flag   = (int*)alloc(256);
    if (off > ws_size) return;

    hipMemsetAsync(deg, 0, (size_t)NSEG * 4, stream);
    hipMemsetAsync(cnt, 0, (size_t)NSEG * 4, stream);

    detect_kernel<<<1, 64, 0, stream>>>((const unsigned int*)E, flag);
    prep_pt_kernel<<<HID, 256, 0, stream>>>(P, Pt);
    prep_wt_kernel<<<HID, 256, 0, stream>>>(W, Wt);

    deg_cnt_kernel<<<NEDGE / 256, 256, 0, stream>>>(E, flag, deg, cnt);
    dinv_kernel<<<(NSEG + 255) / 256, 256, 0, stream>>>(deg, dinv);
    scan1_kernel<<<NBLK, 256, 0, stream>>>(cnt, bsum);
    scan2_kernel<<<1, 256, 0, stream>>>(bsum, boff, rowptr);
    scan3_kernel<<<NBLK, 256, 0, stream>>>(cnt, boff, rowptr, cursor);
    scatter_kernel<<<NEDGE / 256, 256, 0, stream>>>(E, flag, dinv, cursor, colidx, val);

    gemm1_kernel<<<NSEG / 64, 256, 0, stream>>>(S, Pt, raw, xcat);

    prop_kernel<<<NSEG / 4, 256, 0, stream>>>(xcat, rowptr, colidx, val, 0 * HID, 1 * HID, -1, 1.f);
    prop_kernel<<<NSEG / 4, 256, 0, stream>>>(xcat, rowptr, colidx, val, 1 * HID, 2 * HID, 0 * HID, 2.f);
    prop_kernel<<<NSEG / 4, 256, 0, stream>>>(xcat, rowptr, colidx, val, 2 * HID, 3 * HID, 1 * HID, 2.f);
    prop_kernel<<<NSEG / 4, 256, 0, stream>>>(xcat, rowptr, colidx, val, 3 * HID, 4 * HID, 2 * HID, 2.f);

    gemm2_kernel<<<(NSEG + 127) / 128, 512, 0, stream>>>(xcat, Wt, bias, gamma, beta, out);
}